// Round 1
// baseline (333.695 us; speedup 1.0000x reference)
//
#include <hip/hip_runtime.h>

#define GRIDN 64
#define MAXE 32

// ---------------------------------------------------------------------------
// Kernel 1: pack per-primitive data into 3 x float4 (48 B) records.
//   A = (x0, y0, dx, dy)         dx,dy = p1-p0 (fp32 sub, same as ref)
//   B = (w, opac, denom, 0)      denom = max(dx*dx+dy*dy, 1e-12) (ref rounding)
//   C = (r, g, b, 0)
// ---------------------------------------------------------------------------
__global__ void pack_prims(const float* __restrict__ cp,
                           const float* __restrict__ sw,
                           const float* __restrict__ fc,
                           const float* __restrict__ op,
                           float4* __restrict__ packed, int n) {
    int p = blockIdx.x * blockDim.x + threadIdx.x;
    if (p >= n) return;
    float x0 = cp[p * 6 + 0], y0 = cp[p * 6 + 1];
    float x1 = cp[p * 6 + 2], y1 = cp[p * 6 + 3];
    float dx = __fsub_rn(x1, x0);
    float dy = __fsub_rn(y1, y0);
    float dd = __fadd_rn(__fmul_rn(dx, dx), __fmul_rn(dy, dy));
    float denom = fmaxf(dd, 1e-12f);
    packed[p * 3 + 0] = make_float4(x0, y0, dx, dy);
    packed[p * 3 + 1] = make_float4(sw[p], op[p], denom, 0.0f);
    packed[p * 3 + 2] = make_float4(fc[p * 3 + 0], fc[p * 3 + 1], fc[p * 3 + 2], 0.0f);
}

// ---------------------------------------------------------------------------
// Kernel 2: build acceleration grid. One thread per cell; sequential scan over
// primitives reproduces argsort(~mask)[:, :M] (ascending-index first-M) and
// counts = min(total_overlaps, M) exactly.
// cell = ix*G + iy  (ix indexes x / first grid axis, matching the reference).
// ---------------------------------------------------------------------------
__global__ void build_grid(const float* __restrict__ cp,
                           const float* __restrict__ sw,
                           int* __restrict__ entries,
                           int* __restrict__ counts, int nprim) {
    int cell = blockIdx.x * blockDim.x + threadIdx.x;
    if (cell >= GRIDN * GRIDN) return;
    int ixc = cell / GRIDN;
    int iyc = cell % GRIDN;
    float lox = (float)ixc / (float)GRIDN;
    float hix = ((float)ixc + 1.0f) / (float)GRIDN;
    float loy = (float)iyc / (float)GRIDN;
    float hiy = ((float)iyc + 1.0f) / (float)GRIDN;
    int total = 0;
    int* e = entries + (size_t)cell * MAXE;
    for (int p = 0; p < nprim; ++p) {
        float x0 = cp[p * 6 + 0], y0 = cp[p * 6 + 1];
        float x1 = cp[p * 6 + 2], y1 = cp[p * 6 + 3];
        float w = sw[p];
        float xmin = __fsub_rn(fminf(x0, x1), w);
        float xmax = __fadd_rn(fmaxf(x0, x1), w);
        float ymin = __fsub_rn(fminf(y0, y1), w);
        float ymax = __fadd_rn(fmaxf(y0, y1), w);
        bool ov = (xmin < hix) && (xmax >= lox) && (ymin < hiy) && (ymax >= loy);
        if (ov) {
            if (total < MAXE) e[total] = p;
            ++total;
        }
    }
    counts[cell] = total < MAXE ? total : MAXE;
}

// ---------------------------------------------------------------------------
// Kernel 3: render. One thread per sample point. Replicates numpy fp32
// op-by-op rounding (no FMA contraction) so the inside/outside boundary
// decisions match the reference bit-for-bit.
// ---------------------------------------------------------------------------
__global__ __launch_bounds__(256) void render(const float2* __restrict__ xs,
                                              const float4* __restrict__ packed,
                                              const int* __restrict__ entries,
                                              const int* __restrict__ counts,
                                              const float* __restrict__ bg,
                                              float* __restrict__ out, int n) {
    int i = blockIdx.x * blockDim.x + threadIdx.x;
    if (i >= n) return;
    float2 pxy = xs[i];
    float px = pxy.x, py = pxy.y;
    int ix = (int)__fmul_rn(px, (float)GRIDN);
    ix = min(max(ix, 0), GRIDN - 1);
    int iy = (int)__fmul_rn(py, (float)GRIDN);
    iy = min(max(iy, 0), GRIDN - 1);
    int cell = ix * GRIDN + iy;
    int cnt = counts[cell];
    const int* e = entries + (size_t)cell * MAXE;
    float cr = bg[0], cg = bg[1], cb = bg[2];
    for (int s = 0; s < cnt; ++s) {
        int p = e[s];
        float4 A = packed[p * 3 + 0];
        float4 B = packed[p * 3 + 1];
        float4 C = packed[p * 3 + 2];
        float relx = __fsub_rn(px, A.x);
        float rely = __fsub_rn(py, A.y);
        float td = __fadd_rn(__fmul_rn(relx, A.z), __fmul_rn(rely, A.w));
        float t = __fdiv_rn(td, B.z);
        t = fminf(fmaxf(t, 0.0f), 1.0f);
        float qx = __fsub_rn(relx, __fmul_rn(t, A.z));
        float qy = __fsub_rn(rely, __fmul_rn(t, A.w));
        float dist = __fsqrt_rn(__fadd_rn(__fmul_rn(qx, qx), __fmul_rn(qy, qy)));
        float a = (dist <= B.x) ? B.y : 0.0f;
        float om = __fsub_rn(1.0f, a);
        cr = __fadd_rn(__fmul_rn(cr, om), __fmul_rn(C.x, a));
        cg = __fadd_rn(__fmul_rn(cg, om), __fmul_rn(C.y, a));
        cb = __fadd_rn(__fmul_rn(cb, om), __fmul_rn(C.z, a));
    }
    out[(size_t)i * 3 + 0] = cr;
    out[(size_t)i * 3 + 1] = cg;
    out[(size_t)i * 3 + 2] = cb;
}

extern "C" void kernel_launch(void* const* d_in, const int* in_sizes, int n_in,
                              void* d_out, int out_size, void* d_ws, size_t ws_size,
                              hipStream_t stream) {
    const float* x  = (const float*)d_in[0];   // (npts, 2)
    const float* cp = (const float*)d_in[1];   // (nprim, 6)
    const float* sw = (const float*)d_in[2];   // (nprim,)
    const float* fc = (const float*)d_in[3];   // (nprim, 3)
    const float* op = (const float*)d_in[4];   // (nprim,)
    const float* bg = (const float*)d_in[5];   // (3,)
    float* out = (float*)d_out;

    int npts  = in_sizes[0] / 2;
    int nprim = in_sizes[2];

    // workspace layout: [0, 64K)   packed prims (nprim*48 B)
    //                   [64K, 576K) entries (4096*32*4 B)
    //                   [576K, 592K) counts (4096*4 B)
    char* ws = (char*)d_ws;
    float4* packed = (float4*)ws;
    int* entries   = (int*)(ws + 64 * 1024);
    int* counts    = (int*)(ws + 64 * 1024 + 512 * 1024);

    pack_prims<<<(nprim + 255) / 256, 256, 0, stream>>>(cp, sw, fc, op, packed, nprim);
    build_grid<<<(GRIDN * GRIDN + 255) / 256, 256, 0, stream>>>(cp, sw, entries, counts, nprim);
    render<<<(npts + 255) / 256, 256, 0, stream>>>((const float2*)x, packed, entries,
                                                   counts, bg, out, npts);
}

// Round 2
// 151.734 us; speedup vs baseline: 2.1992x; 2.1992x over previous
//
#include <hip/hip_runtime.h>

#define GRIDN 64
#define MAXE 32

// ---------------------------------------------------------------------------
// Kernel 1: pack per-primitive data.
//   packed[p*3+0] = (x0, y0, dx, dy)
//   packed[p*3+1] = (w, opac, denom, 0)   denom = max(dx*dx+dy*dy, 1e-12)
//   packed[p*3+2] = (r, g, b, 0)
//   aabb[p]      = (xmin, xmax, ymin, ymax)  width-expanded, ref rounding
// ---------------------------------------------------------------------------
__global__ void pack_prims(const float* __restrict__ cp,
                           const float* __restrict__ sw,
                           const float* __restrict__ fc,
                           const float* __restrict__ op,
                           float4* __restrict__ packed,
                           float4* __restrict__ aabb, int n) {
    int p = blockIdx.x * blockDim.x + threadIdx.x;
    if (p >= n) return;
    float x0 = cp[p * 6 + 0], y0 = cp[p * 6 + 1];
    float x1 = cp[p * 6 + 2], y1 = cp[p * 6 + 3];
    float w = sw[p];
    float dx = __fsub_rn(x1, x0);
    float dy = __fsub_rn(y1, y0);
    float dd = __fadd_rn(__fmul_rn(dx, dx), __fmul_rn(dy, dy));
    float denom = fmaxf(dd, 1e-12f);
    packed[p * 3 + 0] = make_float4(x0, y0, dx, dy);
    packed[p * 3 + 1] = make_float4(w, op[p], denom, 0.0f);
    packed[p * 3 + 2] = make_float4(fc[p * 3 + 0], fc[p * 3 + 1], fc[p * 3 + 2], 0.0f);
    float xmin = __fsub_rn(fminf(x0, x1), w);
    float xmax = __fadd_rn(fmaxf(x0, x1), w);
    float ymin = __fsub_rn(fminf(y0, y1), w);
    float ymax = __fadd_rn(fmaxf(y0, y1), w);
    aabb[p] = make_float4(xmin, xmax, ymin, ymax);
}

// ---------------------------------------------------------------------------
// Kernel 2: build acceleration grid — ONE WAVE PER CELL.
// 64 lanes test 64 prims per iteration; __ballot + popcount-prefix performs an
// ordered (ascending prim index) compaction identical to the serial scan, so
// entries == argsort(~mask)[:, :M] and counts == min(total, M) exactly.
// ---------------------------------------------------------------------------
__global__ __launch_bounds__(256) void build_grid(const float4* __restrict__ aabb,
                                                  int* __restrict__ entries,
                                                  int* __restrict__ counts, int nprim) {
    int wave = (int)((blockIdx.x * blockDim.x + threadIdx.x) >> 6);
    int lane = threadIdx.x & 63;
    if (wave >= GRIDN * GRIDN) return;
    int ixc = wave / GRIDN;
    int iyc = wave % GRIDN;
    float lox = (float)ixc / (float)GRIDN;
    float hix = ((float)ixc + 1.0f) / (float)GRIDN;
    float loy = (float)iyc / (float)GRIDN;
    float hiy = ((float)iyc + 1.0f) / (float)GRIDN;
    int total = 0;
    int* e = entries + (size_t)wave * MAXE;
    for (int base = 0; base < nprim; base += 64) {
        int p = base + lane;
        bool ov = false;
        if (p < nprim) {
            float4 bb = aabb[p];
            ov = (bb.x < hix) && (bb.y >= lox) && (bb.z < hiy) && (bb.w >= loy);
        }
        unsigned long long m = __ballot(ov);
        if (ov) {
            int pos = total + (int)__popcll(m & ((1ull << lane) - 1ull));
            if (pos < MAXE) e[pos] = p;
        }
        total += (int)__popcll(m);
    }
    if (lane == 0) counts[wave] = total < MAXE ? total : MAXE;
}

// ---------------------------------------------------------------------------
// Kernel 3: render. One thread per sample point. Replicates numpy fp32
// op-by-op rounding (no FMA contraction) so inside/outside boundary decisions
// match the reference bit-for-bit.
// ---------------------------------------------------------------------------
__global__ __launch_bounds__(256) void render(const float2* __restrict__ xs,
                                              const float4* __restrict__ packed,
                                              const int* __restrict__ entries,
                                              const int* __restrict__ counts,
                                              const float* __restrict__ bg,
                                              float* __restrict__ out, int n) {
    int i = blockIdx.x * blockDim.x + threadIdx.x;
    if (i >= n) return;
    float2 pxy = xs[i];
    float px = pxy.x, py = pxy.y;
    int ix = (int)__fmul_rn(px, (float)GRIDN);
    ix = min(max(ix, 0), GRIDN - 1);
    int iy = (int)__fmul_rn(py, (float)GRIDN);
    iy = min(max(iy, 0), GRIDN - 1);
    int cell = ix * GRIDN + iy;
    int cnt = counts[cell];
    const int* e = entries + (size_t)cell * MAXE;
    float cr = bg[0], cg = bg[1], cb = bg[2];
    for (int s = 0; s < cnt; ++s) {
        int p = e[s];
        float4 A = packed[p * 3 + 0];
        float4 B = packed[p * 3 + 1];
        float4 C = packed[p * 3 + 2];
        float relx = __fsub_rn(px, A.x);
        float rely = __fsub_rn(py, A.y);
        float td = __fadd_rn(__fmul_rn(relx, A.z), __fmul_rn(rely, A.w));
        float t = __fdiv_rn(td, B.z);
        t = fminf(fmaxf(t, 0.0f), 1.0f);
        float qx = __fsub_rn(relx, __fmul_rn(t, A.z));
        float qy = __fsub_rn(rely, __fmul_rn(t, A.w));
        float dist = __fsqrt_rn(__fadd_rn(__fmul_rn(qx, qx), __fmul_rn(qy, qy)));
        float a = (dist <= B.x) ? B.y : 0.0f;
        float om = __fsub_rn(1.0f, a);
        cr = __fadd_rn(__fmul_rn(cr, om), __fmul_rn(C.x, a));
        cg = __fadd_rn(__fmul_rn(cg, om), __fmul_rn(C.y, a));
        cb = __fadd_rn(__fmul_rn(cb, om), __fmul_rn(C.z, a));
    }
    out[(size_t)i * 3 + 0] = cr;
    out[(size_t)i * 3 + 1] = cg;
    out[(size_t)i * 3 + 2] = cb;
}

extern "C" void kernel_launch(void* const* d_in, const int* in_sizes, int n_in,
                              void* d_out, int out_size, void* d_ws, size_t ws_size,
                              hipStream_t stream) {
    const float* x  = (const float*)d_in[0];   // (npts, 2)
    const float* cp = (const float*)d_in[1];   // (nprim, 6)
    const float* sw = (const float*)d_in[2];   // (nprim,)
    const float* fc = (const float*)d_in[3];   // (nprim, 3)
    const float* op = (const float*)d_in[4];   // (nprim,)
    const float* bg = (const float*)d_in[5];   // (3,)
    float* out = (float*)d_out;

    int npts  = in_sizes[0] / 2;
    int nprim = in_sizes[2];

    // workspace layout:
    //   [0,   64K)  packed prims (nprim*48 B)
    //   [64K, 128K) aabb        (nprim*16 B)
    //   [128K,640K) entries     (4096*32*4 B)
    //   [640K,656K) counts      (4096*4 B)
    char* ws = (char*)d_ws;
    float4* packed = (float4*)ws;
    float4* aabb   = (float4*)(ws + 64 * 1024);
    int* entries   = (int*)(ws + 128 * 1024);
    int* counts    = (int*)(ws + 640 * 1024);

    pack_prims<<<(nprim + 255) / 256, 256, 0, stream>>>(cp, sw, fc, op, packed, aabb, nprim);
    // one wave per cell: 4096 waves = 1024 blocks x 256 threads
    build_grid<<<(GRIDN * GRIDN * 64 + 255) / 256, 256, 0, stream>>>(aabb, entries, counts, nprim);
    render<<<(npts + 255) / 256, 256, 0, stream>>>((const float2*)x, packed, entries,
                                                   counts, bg, out, npts);
}

// Round 3
// 80.559 us; speedup vs baseline: 4.1423x; 1.8835x over previous
//
#include <hip/hip_runtime.h>

#define GRIDN 64
#define MAXE 32
#define MAXPRIM 1024   // LDS table sized for up to 1024 prims (dataset: 900)
#define EROW 36        // ints per entry-table row: [cnt, e0..e31, pad x3]

// ---------------------------------------------------------------------------
// Kernel 1: pack per-primitive data.
//   packed[p*3+0] = (x0, y0, dx, dy)
//   packed[p*3+1] = (w, opac, denom, 0)   denom = max(dx*dx+dy*dy, 1e-12)
//   packed[p*3+2] = (r, g, b, 0)
//   aabb[p]      = (xmin, xmax, ymin, ymax)  width-expanded, ref rounding
// ---------------------------------------------------------------------------
__global__ void pack_prims(const float* __restrict__ cp,
                           const float* __restrict__ sw,
                           const float* __restrict__ fc,
                           const float* __restrict__ op,
                           float4* __restrict__ packed,
                           float4* __restrict__ aabb, int n) {
    int p = blockIdx.x * blockDim.x + threadIdx.x;
    if (p >= n) return;
    float x0 = cp[p * 6 + 0], y0 = cp[p * 6 + 1];
    float x1 = cp[p * 6 + 2], y1 = cp[p * 6 + 3];
    float w = sw[p];
    float dx = __fsub_rn(x1, x0);
    float dy = __fsub_rn(y1, y0);
    float dd = __fadd_rn(__fmul_rn(dx, dx), __fmul_rn(dy, dy));
    float denom = fmaxf(dd, 1e-12f);
    packed[p * 3 + 0] = make_float4(x0, y0, dx, dy);
    packed[p * 3 + 1] = make_float4(w, op[p], denom, 0.0f);
    packed[p * 3 + 2] = make_float4(fc[p * 3 + 0], fc[p * 3 + 1], fc[p * 3 + 2], 0.0f);
    float xmin = __fsub_rn(fminf(x0, x1), w);
    float xmax = __fadd_rn(fmaxf(x0, x1), w);
    float ymin = __fsub_rn(fminf(y0, y1), w);
    float ymax = __fadd_rn(fmaxf(y0, y1), w);
    aabb[p] = make_float4(xmin, xmax, ymin, ymax);
}

// ---------------------------------------------------------------------------
// Kernel 2: build grid — one wave per cell. Row layout: [cnt, e0..e31, pad].
// Ballot+popcount prefix reproduces ascending-index first-M + clamped count.
// ---------------------------------------------------------------------------
__global__ __launch_bounds__(256) void build_grid(const float4* __restrict__ aabb,
                                                  int* __restrict__ etab, int nprim) {
    int wave = (int)((blockIdx.x * blockDim.x + threadIdx.x) >> 6);
    int lane = threadIdx.x & 63;
    if (wave >= GRIDN * GRIDN) return;
    int ixc = wave / GRIDN;
    int iyc = wave % GRIDN;
    float lox = (float)ixc / (float)GRIDN;
    float hix = ((float)ixc + 1.0f) / (float)GRIDN;
    float loy = (float)iyc / (float)GRIDN;
    float hiy = ((float)iyc + 1.0f) / (float)GRIDN;
    int total = 0;
    int* row = etab + (size_t)wave * EROW;
    for (int base = 0; base < nprim; base += 64) {
        int p = base + lane;
        bool ov = false;
        if (p < nprim) {
            float4 bb = aabb[p];
            ov = (bb.x < hix) && (bb.y >= lox) && (bb.z < hiy) && (bb.w >= loy);
        }
        unsigned long long m = __ballot(ov);
        if (ov) {
            int pos = total + (int)__popcll(m & ((1ull << lane) - 1ull));
            if (pos < MAXE) row[1 + pos] = p;
        }
        total += (int)__popcll(m);
    }
    if (lane == 0) row[0] = total < MAXE ? total : MAXE;
}

// ---------------------------------------------------------------------------
// Kernel 3: render. Prim table staged in LDS (49 KB -> 2 blocks/CU, 32 waves).
// Entries read as int4 chunks (4 per gather, count folded into first chunk).
// Numerics replicate numpy fp32 op-by-op (no FMA contraction).
// ---------------------------------------------------------------------------
__global__ __launch_bounds__(1024) void render(const float2* __restrict__ xs,
                                               const float4* __restrict__ packed,
                                               const int* __restrict__ etab,
                                               const float* __restrict__ bg,
                                               float* __restrict__ out, int n, int nprim) {
    __shared__ float4 sprim[MAXPRIM * 3];
    for (int t = threadIdx.x; t < nprim * 3; t += blockDim.x) sprim[t] = packed[t];
    __syncthreads();

    int i = blockIdx.x * blockDim.x + threadIdx.x;
    if (i >= n) return;
    float2 pxy = xs[i];
    float px = pxy.x, py = pxy.y;
    int ix = (int)__fmul_rn(px, (float)GRIDN);
    ix = min(max(ix, 0), GRIDN - 1);
    int iy = (int)__fmul_rn(py, (float)GRIDN);
    iy = min(max(iy, 0), GRIDN - 1);
    int row = (ix * GRIDN + iy) * EROW;

    float cr = bg[0], cg = bg[1], cb = bg[2];

#define DO_PRIM(pidx)                                                          \
    {                                                                          \
        int p3 = (pidx) * 3;                                                   \
        float4 A = sprim[p3 + 0];                                              \
        float4 B = sprim[p3 + 1];                                              \
        float4 C = sprim[p3 + 2];                                              \
        float relx = __fsub_rn(px, A.x);                                       \
        float rely = __fsub_rn(py, A.y);                                       \
        float td = __fadd_rn(__fmul_rn(relx, A.z), __fmul_rn(rely, A.w));      \
        float t = __fdiv_rn(td, B.z);                                          \
        t = fminf(fmaxf(t, 0.0f), 1.0f);                                       \
        float qx = __fsub_rn(relx, __fmul_rn(t, A.z));                         \
        float qy = __fsub_rn(rely, __fmul_rn(t, A.w));                         \
        float dist = __fsqrt_rn(__fadd_rn(__fmul_rn(qx, qx), __fmul_rn(qy, qy))); \
        float a = (dist <= B.x) ? B.y : 0.0f;                                  \
        float om = __fsub_rn(1.0f, a);                                         \
        cr = __fadd_rn(__fmul_rn(cr, om), __fmul_rn(C.x, a));                  \
        cg = __fadd_rn(__fmul_rn(cg, om), __fmul_rn(C.y, a));                  \
        cb = __fadd_rn(__fmul_rn(cb, om), __fmul_rn(C.z, a));                  \
    }

    int4 c0 = *(const int4*)(etab + row);   // cnt, e0, e1, e2
    int cnt = c0.x;
    if (cnt > 0) DO_PRIM(c0.y);
    if (cnt > 1) DO_PRIM(c0.z);
    if (cnt > 2) DO_PRIM(c0.w);
    for (int base = 3; base < cnt; base += 4) {
        int4 c = *(const int4*)(etab + row + 1 + base);  // 16B-aligned: 1+base ∈ {4,8,...}
        if (base + 0 < cnt) DO_PRIM(c.x);
        if (base + 1 < cnt) DO_PRIM(c.y);
        if (base + 2 < cnt) DO_PRIM(c.z);
        if (base + 3 < cnt) DO_PRIM(c.w);
    }
#undef DO_PRIM

    out[(size_t)i * 3 + 0] = cr;
    out[(size_t)i * 3 + 1] = cg;
    out[(size_t)i * 3 + 2] = cb;
}

extern "C" void kernel_launch(void* const* d_in, const int* in_sizes, int n_in,
                              void* d_out, int out_size, void* d_ws, size_t ws_size,
                              hipStream_t stream) {
    const float* x  = (const float*)d_in[0];   // (npts, 2)
    const float* cp = (const float*)d_in[1];   // (nprim, 6)
    const float* sw = (const float*)d_in[2];   // (nprim,)
    const float* fc = (const float*)d_in[3];   // (nprim, 3)
    const float* op = (const float*)d_in[4];   // (nprim,)
    const float* bg = (const float*)d_in[5];   // (3,)
    float* out = (float*)d_out;

    int npts  = in_sizes[0] / 2;
    int nprim = in_sizes[2];

    // workspace layout (16B-aligned):
    //   [0,      49152)  packed prims (MAXPRIM*48 B)
    //   [49152,  65536)  aabb         (MAXPRIM*16 B)
    //   [65536,  655360) etab         (4096*36*4 B = 589824)
    char* ws = (char*)d_ws;
    float4* packed = (float4*)ws;
    float4* aabb   = (float4*)(ws + 49152);
    int* etab      = (int*)(ws + 65536);

    pack_prims<<<(nprim + 255) / 256, 256, 0, stream>>>(cp, sw, fc, op, packed, aabb, nprim);
    build_grid<<<(GRIDN * GRIDN * 64 + 255) / 256, 256, 0, stream>>>(aabb, etab, nprim);
    render<<<(npts + 1023) / 1024, 1024, 0, stream>>>((const float2*)x, packed, etab,
                                                      bg, out, npts, nprim);
}

// Round 4
// 59.331 us; speedup vs baseline: 5.6243x; 1.3578x over previous
//
#include <hip/hip_runtime.h>
#include <math.h>

#define GRIDN 64
#define MAXE 32
#define MAXPRIM 1024
#define EROW 36    // ints per entry row: [cnt, e0..e31, pad x3], 144 B (16B aligned)

// ---------------------------------------------------------------------------
// Kernel 1: grid build (one wave per cell, aabb staged in LDS) + pack fused
// into block 0.
//  packed2[p*2+0] = (x0, y0, dx, dy)
//  packed2[p*2+1] = (Tf, inv_lo, inv_hi, 0)   Tf: float threshold with
//      s <= Tf  <=>  rn_f32(sqrt(s)) <= w  (exact; ties-to-even handled)
//      inv = rn_f64(1.0 / denom), denom = max(dx*dx+dy*dy, 1e-12)
//  colors[p]     = (r, g, b, opac)
// ---------------------------------------------------------------------------
__global__ __launch_bounds__(1024) void prep(const float* __restrict__ cp,
                                             const float* __restrict__ sw,
                                             const float* __restrict__ fc,
                                             const float* __restrict__ op,
                                             float4* __restrict__ packed2,
                                             float4* __restrict__ colors,
                                             int* __restrict__ etab, int nprim) {
    __shared__ float4 saabb[MAXPRIM];
    int tid = threadIdx.x;
    for (int p = tid; p < nprim; p += 1024) {
        float x0 = cp[p * 6 + 0], y0 = cp[p * 6 + 1];
        float x1 = cp[p * 6 + 2], y1 = cp[p * 6 + 3];
        float w = sw[p];
        saabb[p] = make_float4(__fsub_rn(fminf(x0, x1), w), __fadd_rn(fmaxf(x0, x1), w),
                               __fsub_rn(fminf(y0, y1), w), __fadd_rn(fmaxf(y0, y1), w));
    }
    __syncthreads();

    int wid = tid >> 6, lane = tid & 63;
    int cell = blockIdx.x * 16 + wid;           // 256 blocks x 16 waves = 4096 cells
    int ixc = cell >> 6, iyc = cell & 63;
    float lox = (float)ixc * (1.0f / GRIDN);    // exact (pow2), == arange/G
    float hix = (float)(ixc + 1) * (1.0f / GRIDN);
    float loy = (float)iyc * (1.0f / GRIDN);
    float hiy = (float)(iyc + 1) * (1.0f / GRIDN);
    int total = 0;
    int* row = etab + (size_t)cell * EROW;
    for (int base = 0; base < nprim; base += 64) {
        int p = base + lane;
        bool ov = false;
        if (p < nprim) {
            float4 bb = saabb[p];
            ov = (bb.x < hix) && (bb.y >= lox) && (bb.z < hiy) && (bb.w >= loy);
        }
        unsigned long long m = __ballot(ov);
        if (ov) {
            int pos = total + (int)__popcll(m & ((1ull << lane) - 1ull));
            if (pos < MAXE) row[1 + pos] = p;
        }
        total += (int)__popcll(m);
    }
    if (lane == 0) row[0] = total < MAXE ? total : MAXE;

    // --- fused pack (block 0 only) ---
    if (blockIdx.x == 0) {
        for (int p = tid; p < nprim; p += 1024) {
            float x0 = cp[p * 6 + 0], y0 = cp[p * 6 + 1];
            float x1 = cp[p * 6 + 2], y1 = cp[p * 6 + 3];
            float w = sw[p];
            float dx = __fsub_rn(x1, x0);
            float dy = __fsub_rn(y1, y0);
            float dd = __fadd_rn(__fmul_rn(dx, dx), __fmul_rn(dy, dy));
            float denom = fmaxf(dd, 1e-12f);
            double inv = 1.0 / (double)denom;
            // threshold Tf: s <= Tf <=> rn_f32(sqrt(s)) <= w
            unsigned wb = __float_as_uint(w);
            bool even = (wb & 1u) == 0u;
            float wn = __uint_as_float(wb + 1u);        // w > 0, finite
            double md = 0.5 * ((double)w + (double)wn); // exact
            double m2 = md * md;                        // exact (<=50-bit mantissa)
            float Tf = (float)m2;
            if ((double)Tf > m2) Tf = __uint_as_float(__float_as_uint(Tf) - 1u);
            if (!even && (double)Tf == m2) Tf = __uint_as_float(__float_as_uint(Tf) - 1u);
            unsigned long long ib = __double_as_longlong(inv);
            packed2[p * 2 + 0] = make_float4(x0, y0, dx, dy);
            packed2[p * 2 + 1] = make_float4(Tf,
                                             __uint_as_float((unsigned)(ib & 0xffffffffull)),
                                             __uint_as_float((unsigned)(ib >> 32)),
                                             0.0f);
            colors[p] = make_float4(fc[p * 3 + 0], fc[p * 3 + 1], fc[p * 3 + 2], op[p]);
        }
    }
}

// ---------------------------------------------------------------------------
// Kernel 2: render. Prim geometry (32 KB) + colors (16 KB) staged in LDS.
// Fast path (all opacities == 1.0, detected per block): last-inside-wins
// winner tracking — no color reads / composite math in the inner loop.
// Fallback path: full exact compositing.
// t = (float)((double)td * inv) matches rn(td/denom) except w.p. ~1e-8;
// inside test s <= Tf is exactly equivalent to rn(sqrt(s)) <= w.
// ---------------------------------------------------------------------------
__global__ __launch_bounds__(1024) void render(const float2* __restrict__ xs,
                                               const float4* __restrict__ packed2,
                                               const float4* __restrict__ colors,
                                               const int* __restrict__ etab,
                                               const float* __restrict__ bg,
                                               float* __restrict__ out, int n, int nprim) {
    __shared__ float4 sAB[MAXPRIM * 2];
    __shared__ float4 scol[MAXPRIM];
    __shared__ int sflag;
    if (threadIdx.x == 0) sflag = 0;
    __syncthreads();

    int i = blockIdx.x * 1024 + threadIdx.x;
    bool valid = i < n;
    float px = 0.0f, py = 0.0f;
    int row = 0;
    int4 c0 = make_int4(0, 0, 0, 0), c1 = make_int4(0, 0, 0, 0);
    if (valid) {
        float2 pxy = xs[i];
        px = pxy.x; py = pxy.y;
        int ix = (int)__fmul_rn(px, (float)GRIDN);
        ix = min(max(ix, 0), GRIDN - 1);
        int iy = (int)__fmul_rn(py, (float)GRIDN);
        iy = min(max(iy, 0), GRIDN - 1);
        row = (ix * GRIDN + iy) * EROW;
        c0 = *(const int4*)(etab + row);        // cnt, e0, e1, e2
        c1 = *(const int4*)(etab + row + 4);    // e3..e6
    }

    for (int t = threadIdx.x; t < nprim; t += 1024) {
        sAB[t * 2 + 0] = packed2[t * 2 + 0];
        sAB[t * 2 + 1] = packed2[t * 2 + 1];
        float4 c = colors[t];
        scol[t] = c;
        if (c.w != 1.0f) sflag = 1;   // benign race, same value
    }
    __syncthreads();

    int cnt = valid ? c0.x : 0;

#define CORE(pidx)                                                             \
    int p = (pidx);                                                            \
    float4 A = sAB[p * 2 + 0];                                                 \
    float4 Bv = sAB[p * 2 + 1];                                                \
    float relx = __fsub_rn(px, A.x);                                           \
    float rely = __fsub_rn(py, A.y);                                           \
    float td = __fadd_rn(__fmul_rn(relx, A.z), __fmul_rn(rely, A.w));          \
    double inv = __hiloint2double(__float_as_int(Bv.z), __float_as_int(Bv.y)); \
    float t = (float)((double)td * inv);                                       \
    t = fminf(fmaxf(t, 0.0f), 1.0f);                                           \
    float qx = __fsub_rn(relx, __fmul_rn(t, A.z));                             \
    float qy = __fsub_rn(rely, __fmul_rn(t, A.w));                             \
    float s = __fadd_rn(__fmul_rn(qx, qx), __fmul_rn(qy, qy));

    if (sflag == 0) {
        // ---- fast path: all opacities == 1.0 -> last inside prim wins ----
        int win = -1;
#define TESTW(pidx) { CORE(pidx); if (s <= Bv.x) win = p; }
        if (cnt > 0) TESTW(c0.y);
        if (cnt > 1) TESTW(c0.z);
        if (cnt > 2) TESTW(c0.w);
        if (cnt > 3) TESTW(c1.x);
        if (cnt > 4) TESTW(c1.y);
        if (cnt > 5) TESTW(c1.z);
        if (cnt > 6) TESTW(c1.w);
        for (int base = 7; base < cnt; base += 4) {
            int4 c = *(const int4*)(etab + row + 1 + base);   // 1+7=8: 16B aligned
            if (base + 0 < cnt) TESTW(c.x);
            if (base + 1 < cnt) TESTW(c.y);
            if (base + 2 < cnt) TESTW(c.z);
            if (base + 3 < cnt) TESTW(c.w);
        }
#undef TESTW
        if (valid) {
            float cr, cg, cb;
            if (win >= 0) {
                float4 C = scol[win];
                cr = C.x; cg = C.y; cb = C.z;
            } else {
                cr = bg[0]; cg = bg[1]; cb = bg[2];
            }
            out[(size_t)i * 3 + 0] = cr;
            out[(size_t)i * 3 + 1] = cg;
            out[(size_t)i * 3 + 2] = cb;
        }
    } else {
        // ---- general path: exact composite ----
        float cr = bg[0], cg = bg[1], cb = bg[2];
#define TESTC(pidx) { CORE(pidx);                                              \
        float4 C = scol[p];                                                    \
        float a = (s <= Bv.x) ? C.w : 0.0f;                                    \
        float om = __fsub_rn(1.0f, a);                                         \
        cr = __fadd_rn(__fmul_rn(cr, om), __fmul_rn(C.x, a));                  \
        cg = __fadd_rn(__fmul_rn(cg, om), __fmul_rn(C.y, a));                  \
        cb = __fadd_rn(__fmul_rn(cb, om), __fmul_rn(C.z, a)); }
        if (cnt > 0) TESTC(c0.y);
        if (cnt > 1) TESTC(c0.z);
        if (cnt > 2) TESTC(c0.w);
        if (cnt > 3) TESTC(c1.x);
        if (cnt > 4) TESTC(c1.y);
        if (cnt > 5) TESTC(c1.z);
        if (cnt > 6) TESTC(c1.w);
        for (int base = 7; base < cnt; base += 4) {
            int4 c = *(const int4*)(etab + row + 1 + base);
            if (base + 0 < cnt) TESTC(c.x);
            if (base + 1 < cnt) TESTC(c.y);
            if (base + 2 < cnt) TESTC(c.z);
            if (base + 3 < cnt) TESTC(c.w);
        }
#undef TESTC
        if (valid) {
            out[(size_t)i * 3 + 0] = cr;
            out[(size_t)i * 3 + 1] = cg;
            out[(size_t)i * 3 + 2] = cb;
        }
    }
#undef CORE
}

extern "C" void kernel_launch(void* const* d_in, const int* in_sizes, int n_in,
                              void* d_out, int out_size, void* d_ws, size_t ws_size,
                              hipStream_t stream) {
    const float* x  = (const float*)d_in[0];   // (npts, 2)
    const float* cp = (const float*)d_in[1];   // (nprim, 6)
    const float* sw = (const float*)d_in[2];   // (nprim,)
    const float* fc = (const float*)d_in[3];   // (nprim, 3)
    const float* op = (const float*)d_in[4];   // (nprim,)
    const float* bg = (const float*)d_in[5];   // (3,)
    float* out = (float*)d_out;

    int npts  = in_sizes[0] / 2;
    int nprim = in_sizes[2];

    // workspace layout (16B aligned):
    //   [0,     32768)  packed2 (MAXPRIM*32 B)
    //   [32768, 49152)  colors  (MAXPRIM*16 B)
    //   [49152, 638976) etab    (4096*36*4 B)
    char* ws = (char*)d_ws;
    float4* packed2 = (float4*)ws;
    float4* colors  = (float4*)(ws + 32768);
    int* etab       = (int*)(ws + 49152);

    prep<<<GRIDN * GRIDN / 16, 1024, 0, stream>>>(cp, sw, fc, op, packed2, colors, etab, nprim);
    render<<<(npts + 1023) / 1024, 1024, 0, stream>>>((const float2*)x, packed2, colors,
                                                      etab, bg, out, npts, nprim);
}